// Round 1
// baseline (39.936 us; speedup 1.0000x reference)
//
#include <hip/hip_runtime.h>

// Problem constants (fixed by the reference).
#define S_ENC 512      // encoder image size
#define IN_WH 1024     // input H == W
#define NB 4           // batch
#define NQ 8           // queries
#define NPTS 4         // points per query
// radius = 5 -> r2 = 25, gated fill = 26

// ---------------------------------------------------------------------------
// Kernel 1: bilinear 2x downsample (== 2x2 average, align_corners=False) +
// normalize, into workspace laid out as [B*3][512][512] fp32.
// grid: (256, 12), block 256. Each thread produces 4 consecutive output x.
// ---------------------------------------------------------------------------
__global__ __launch_bounds__(256) void resize_norm_kernel(
    const float* __restrict__ img,   // [B][3][1024][1024]
    const float* __restrict__ mean,  // [3]
    const float* __restrict__ stdv,  // [3]
    float* __restrict__ wimg)        // [B*3][512][512]
{
  const int bc  = blockIdx.y;                        // b*3 + c, 0..11 (block-uniform)
  const int tid = blockIdx.x * 256 + threadIdx.x;    // 0..65535
  const int y   = tid >> 7;                          // 0..511
  const int x4  = (tid & 127) << 2;                  // 0,4,...,508

  const float m = mean[bc % 3];
  const float s = stdv[bc % 3];

  const float* in0 = img + ((size_t)bc * IN_WH + (size_t)(2 * y)) * IN_WH + 2 * x4;
  const float4 a0 = *(const float4*)(in0);
  const float4 a1 = *(const float4*)(in0 + 4);
  const float4 b0 = *(const float4*)(in0 + IN_WH);
  const float4 b1 = *(const float4*)(in0 + IN_WH + 4);

  float4 r;
  r.x = 0.5f * (0.5f * (a0.x + a0.y) + 0.5f * (b0.x + b0.y));
  r.y = 0.5f * (0.5f * (a0.z + a0.w) + 0.5f * (b0.z + b0.w));
  r.z = 0.5f * (0.5f * (a1.x + a1.y) + 0.5f * (b1.x + b1.y));
  r.w = 0.5f * (0.5f * (a1.z + a1.w) + 0.5f * (b1.z + b1.w));
  r.x = (r.x - m) / s;
  r.y = (r.y - m) / s;
  r.z = (r.z - m) / s;
  r.w = (r.w - m) / s;

  *(float4*)(wimg + ((size_t)bc * S_ENC + y) * S_ENC + x4) = r;
}

// ---------------------------------------------------------------------------
// Kernel 2: write fused output [B*Q][5][512][512].
//   c in 0..2 : copy normalized resized image (from ws, or computed inline)
//   c == 3    : bbox mask from first two points (or full image if label0==1)
//   c == 4    : circle mask: min over label==1 points of squared dist <= 25
// grid: (256, 160), block 256. plane = bq*5 + c is block-uniform.
// Mask math uses __fmul_rn/__fadd_rn to forbid FMA contraction -> bit-exact
// squared distances vs numpy (a flipped mask bit would be absmax 1.0).
// ---------------------------------------------------------------------------
template <bool UseWs>
__global__ __launch_bounds__(256) void fuse_kernel(
    const float* __restrict__ wimg,    // [B*3][512][512] (UseWs) or nullptr
    const float* __restrict__ img,     // [B][3][1024][1024] (fallback)
    const float* __restrict__ pts,     // [B][Q][P][2]
    const int*   __restrict__ labels,  // [B][Q][P]
    const float* __restrict__ mean,    // [3]
    const float* __restrict__ stdv,    // [3]
    float* __restrict__ out)           // [B*Q][5][512][512]
{
  const int plane = blockIdx.y;        // bq*5 + c, 0..159 (block-uniform)
  const int c  = plane % 5;
  const int bq = plane / 5;
  const int b  = bq >> 3;              // NQ == 8
  const int q  = bq & 7;

  const int tid = blockIdx.x * 256 + threadIdx.x;  // 0..65535
  const int y   = tid >> 7;
  const int x4  = (tid & 127) << 2;

  float4 r;

  if (c < 3) {
    if (UseWs) {
      r = *(const float4*)(wimg + ((size_t)(b * 3 + c) * S_ENC + y) * S_ENC + x4);
    } else {
      const float m = mean[c];
      const float s = stdv[c];
      const float* in0 =
          img + ((size_t)(b * 3 + c) * IN_WH + (size_t)(2 * y)) * IN_WH + 2 * x4;
      const float4 a0 = *(const float4*)(in0);
      const float4 a1 = *(const float4*)(in0 + 4);
      const float4 b0 = *(const float4*)(in0 + IN_WH);
      const float4 b1 = *(const float4*)(in0 + IN_WH + 4);
      r.x = 0.5f * (0.5f * (a0.x + a0.y) + 0.5f * (b0.x + b0.y));
      r.y = 0.5f * (0.5f * (a0.z + a0.w) + 0.5f * (b0.z + b0.w));
      r.z = 0.5f * (0.5f * (a1.x + a1.y) + 0.5f * (b1.x + b1.y));
      r.w = 0.5f * (0.5f * (a1.z + a1.w) + 0.5f * (b1.z + b1.w));
      r.x = (r.x - m) / s;
      r.y = (r.y - m) / s;
      r.z = (r.z - m) / s;
      r.w = (r.w - m) / s;
    }
  } else {
    // Per-(b,q) point data: addresses are block-uniform -> scalar loads.
    const float* p   = pts + (size_t)(bq) * NPTS * 2;
    const int*   lab = labels + (size_t)(bq) * NPTS;
    float px[NPTS], py[NPTS];
    int   lb[NPTS];
#pragma unroll
    for (int i = 0; i < NPTS; ++i) {
      const float vx = p[2 * i + 0];
      const float vy = p[2 * i + 1];
      px[i] = (vx >= 0.0f) ? __fmul_rn(vx, 0.5f) : -1.0f;  // * (512/1024)
      py[i] = (vy >= 0.0f) ? __fmul_rn(vy, 0.5f) : -1.0f;
      lb[i] = lab[i];
    }
    const float fy = (float)y;
    float* rr = &r.x;

    if (c == 3) {
      float tlx, tly, brx, bry;
      if (lb[0] != 1) {  // is_bbox
        tlx = fminf(px[0], px[1]);
        tly = fminf(py[0], py[1]);
        brx = fmaxf(px[0], px[1]);
        bry = fmaxf(py[0], py[1]);
      } else {
        tlx = 0.0f; tly = 0.0f;
        brx = (float)S_ENC; bry = (float)S_ENC;
      }
      const bool rowok = (fy >= tly) && (fy <= bry);
#pragma unroll
      for (int j = 0; j < 4; ++j) {
        const float fx = (float)(x4 + j);
        rr[j] = (rowok && fx >= tlx && fx <= brx) ? 1.0f : 0.0f;
      }
    } else {  // c == 4 : circle mask
#pragma unroll
      for (int j = 0; j < 4; ++j) {
        const float fx = (float)(x4 + j);
        float mind = 26.0f;  // r2 + 1 (value for non-point-labeled entries)
#pragma unroll
        for (int i = 0; i < NPTS; ++i) {
          if (lb[i] == 1) {
            const float dx = __fsub_rn(fx, px[i]);
            const float dy = __fsub_rn(fy, py[i]);
            const float d2 = __fadd_rn(__fmul_rn(dx, dx), __fmul_rn(dy, dy));
            mind = fminf(mind, d2);
          }
        }
        rr[j] = (mind <= 25.0f) ? 1.0f : 0.0f;
      }
    }
  }

  *(float4*)(out + ((size_t)plane * S_ENC + y) * S_ENC + x4) = r;
}

// ---------------------------------------------------------------------------
extern "C" void kernel_launch(void* const* d_in, const int* in_sizes, int n_in,
                              void* d_out, int out_size, void* d_ws, size_t ws_size,
                              hipStream_t stream) {
  const float* img    = (const float*)d_in[0];  // [4][3][1024][1024] f32
  const float* pts    = (const float*)d_in[1];  // [4][8][4][2] f32
  const int*   labels = (const int*)d_in[2];    // [4][8][4] i32
  const float* mean   = (const float*)d_in[3];  // [1][3][1][1] f32
  const float* stdv   = (const float*)d_in[4];  // [1][3][1][1] f32
  float* out = (float*)d_out;                   // [32][5][512][512] f32

  const size_t ws_need = (size_t)NB * 3 * S_ENC * S_ENC * sizeof(float);

  if (d_ws != nullptr && ws_size >= ws_need) {
    float* wimg = (float*)d_ws;
    dim3 g1(256, NB * 3);
    resize_norm_kernel<<<g1, 256, 0, stream>>>(img, mean, stdv, wimg);
    dim3 g2(256, NB * NQ * 5);
    fuse_kernel<true><<<g2, 256, 0, stream>>>(wimg, img, pts, labels, mean, stdv, out);
  } else {
    dim3 g2(256, NB * NQ * 5);
    fuse_kernel<false><<<g2, 256, 0, stream>>>(nullptr, img, pts, labels, mean, stdv, out);
  }
}

// Round 2
// 36.617 us; speedup vs baseline: 1.0906x; 1.0906x over previous
//
#include <hip/hip_runtime.h>

// Problem constants (fixed by the reference).
#define S_ENC 512      // encoder image size
#define IN_WH 1024     // input H == W
#define NB 4           // batch
#define NQ 8           // queries
#define NPTS 4         // points per query
#define PLANE_STRIDE (5 * S_ENC * S_ENC)   // floats between consecutive bq planes
// radius = 5 -> r2 = 25, gated fill = 26

// ---------------------------------------------------------------------------
// Single fused kernel. blockIdx.y selects a "job":
//   job <  12          : image job bc = b*3+c. Compute 2x2-avg downsample +
//                        normalize of one (b,c) plane; store the SAME float4
//                        to all 8 q-replica output planes (compulsory bytes —
//                        no workspace round-trip).
//   job >= 12 (64 jobs): mask job. idx = job-12; bq = idx>>1;
//                        c = 3 + (idx&1)  -> bbox mask or circle mask.
// grid: (256, 76), block 256; each thread handles one float4 (y = tid>>7,
// x4 = (tid&127)<<2). All job parameters are block-uniform -> scalar loads,
// no divergence.
// Mask math uses __f*_rn to forbid FMA contraction -> bit-exact squared
// distances vs numpy (one flipped mask bit = absmax 1.0 > threshold).
// ---------------------------------------------------------------------------
__global__ __launch_bounds__(256) void early_fusion_kernel(
    const float* __restrict__ img,     // [B][3][1024][1024]
    const float* __restrict__ pts,     // [B][Q][P][2]
    const int*   __restrict__ labels,  // [B][Q][P]
    const float* __restrict__ mean,    // [3]
    const float* __restrict__ stdv,    // [3]
    float* __restrict__ out)           // [B*Q][5][512][512]
{
  const int job = blockIdx.y;
  const int tid = blockIdx.x * 256 + threadIdx.x;  // 0..65535
  const int y   = tid >> 7;                        // 0..511
  const int x4  = (tid & 127) << 2;                // 0,4,...,508

  if (job < NB * 3) {
    // ---- image job: resize+normalize, fan-out store to 8 planes ----
    const int bc = job;          // b*3 + c
    const int b  = bc / 3;
    const int c  = bc % 3;
    const float m = mean[c];
    const float s = stdv[c];

    const float* in0 =
        img + ((size_t)bc * IN_WH + (size_t)(2 * y)) * IN_WH + 2 * x4;
    const float4 a0 = *(const float4*)(in0);
    const float4 a1 = *(const float4*)(in0 + 4);
    const float4 b0 = *(const float4*)(in0 + IN_WH);
    const float4 b1 = *(const float4*)(in0 + IN_WH + 4);

    float4 r;
    r.x = 0.5f * (0.5f * (a0.x + a0.y) + 0.5f * (b0.x + b0.y));
    r.y = 0.5f * (0.5f * (a0.z + a0.w) + 0.5f * (b0.z + b0.w));
    r.z = 0.5f * (0.5f * (a1.x + a1.y) + 0.5f * (b1.x + b1.y));
    r.w = 0.5f * (0.5f * (a1.z + a1.w) + 0.5f * (b1.z + b1.w));
    r.x = (r.x - m) / s;
    r.y = (r.y - m) / s;
    r.z = (r.z - m) / s;
    r.w = (r.w - m) / s;

    // plane (b*8+q)*5 + c, q = 0..7
    float* dst = out + ((size_t)(b * NQ * 5 + c) * S_ENC + y) * S_ENC + x4;
#pragma unroll
    for (int q = 0; q < NQ; ++q) {
      *(float4*)(dst) = r;
      dst += PLANE_STRIDE;
    }
  } else {
    // ---- mask job ----
    const int idx = job - NB * 3;    // 0..63
    const int bq  = idx >> 1;        // 0..31
    const int c   = 3 + (idx & 1);   // 3 or 4

    const float* p   = pts + (size_t)bq * NPTS * 2;
    const int*   lab = labels + (size_t)bq * NPTS;
    float px[NPTS], py[NPTS];
    int   lb[NPTS];
#pragma unroll
    for (int i = 0; i < NPTS; ++i) {
      const float vx = p[2 * i + 0];
      const float vy = p[2 * i + 1];
      px[i] = (vx >= 0.0f) ? __fmul_rn(vx, 0.5f) : -1.0f;  // * (512/1024)
      py[i] = (vy >= 0.0f) ? __fmul_rn(vy, 0.5f) : -1.0f;
      lb[i] = lab[i];
    }
    const float fy = (float)y;
    float4 r;
    float* rr = &r.x;

    if (c == 3) {
      float tlx, tly, brx, bry;
      if (lb[0] != 1) {  // is_bbox
        tlx = fminf(px[0], px[1]);
        tly = fminf(py[0], py[1]);
        brx = fmaxf(px[0], px[1]);
        bry = fmaxf(py[0], py[1]);
      } else {
        tlx = 0.0f; tly = 0.0f;
        brx = (float)S_ENC; bry = (float)S_ENC;
      }
      const bool rowok = (fy >= tly) && (fy <= bry);
#pragma unroll
      for (int j = 0; j < 4; ++j) {
        const float fx = (float)(x4 + j);
        rr[j] = (rowok && fx >= tlx && fx <= brx) ? 1.0f : 0.0f;
      }
    } else {  // c == 4 : circle mask
#pragma unroll
      for (int j = 0; j < 4; ++j) {
        const float fx = (float)(x4 + j);
        float mind = 26.0f;  // r2 + 1 (value for non-point-labeled entries)
#pragma unroll
        for (int i = 0; i < NPTS; ++i) {
          if (lb[i] == 1) {
            const float dx = __fsub_rn(fx, px[i]);
            const float dy = __fsub_rn(fy, py[i]);
            const float d2 = __fadd_rn(__fmul_rn(dx, dx), __fmul_rn(dy, dy));
            mind = fminf(mind, d2);
          }
        }
        rr[j] = (mind <= 25.0f) ? 1.0f : 0.0f;
      }
    }

    *(float4*)(out + ((size_t)(bq * 5 + c) * S_ENC + y) * S_ENC + x4) = r;
  }
}

// ---------------------------------------------------------------------------
extern "C" void kernel_launch(void* const* d_in, const int* in_sizes, int n_in,
                              void* d_out, int out_size, void* d_ws, size_t ws_size,
                              hipStream_t stream) {
  const float* img    = (const float*)d_in[0];  // [4][3][1024][1024] f32
  const float* pts    = (const float*)d_in[1];  // [4][8][4][2] f32
  const int*   labels = (const int*)d_in[2];    // [4][8][4] i32
  const float* mean   = (const float*)d_in[3];  // [1][3][1][1] f32
  const float* stdv   = (const float*)d_in[4];  // [1][3][1][1] f32
  float* out = (float*)d_out;                   // [32][5][512][512] f32

  dim3 grid(256, NB * 3 + NB * NQ * 2);  // 12 image jobs + 64 mask jobs = 76
  early_fusion_kernel<<<grid, 256, 0, stream>>>(img, pts, labels, mean, stdv, out);
}